// Round 1
// baseline (35.901 us; speedup 1.0000x reference)
//
#include <hip/hip_runtime.h>

// LRT loss: ce = -(log_softmax(outputs) * targets).sum()/B
//           lrt = -((A[index] @ soft_labels[index]) * log_softmax(outputs)).sum()/B
// out = ce + (epoch >= 10 ? lrt : 0)
// B=8192, C=64, A is [N,64,64] f32. Memory-bound on the 134 MB A-row gather.

#define CDIM 64

__global__ __launch_bounds__(256) void lrt_stage1(
    const float* __restrict__ outputs,
    const float* __restrict__ targets,
    const float* __restrict__ A,
    const float* __restrict__ soft_labels,
    const int* __restrict__ epoch,
    const int* __restrict__ index,
    float* __restrict__ partial)
{
    const int b = blockIdx.x;
    const int t = threadIdx.x;

    __shared__ float ls_sh[CDIM];   // log_softmax row
    __shared__ float s_sh[CDIM];    // soft_labels[idx]
    __shared__ float red[4];

    const int idx = index[b];
    const float gate = (epoch[0] >= 10) ? 1.0f : 0.0f;

    float ce_part = 0.0f;
    if (t < 64) {  // exactly wave 0 (wave = 64 lanes on CDNA)
        float x = outputs[(size_t)b * CDIM + t];
        float m = x;
        #pragma unroll
        for (int o = 32; o >= 1; o >>= 1) m = fmaxf(m, __shfl_xor(m, o));
        float e = expf(x - m);
        float s = e;
        #pragma unroll
        for (int o = 32; o >= 1; o >>= 1) s += __shfl_xor(s, o);
        float ls = x - m - logf(s);
        ls_sh[t] = ls;
        ce_part = -ls * targets[(size_t)b * CDIM + t];
        s_sh[t] = soft_labels[(size_t)idx * CDIM + t];
    }
    __syncthreads();

    // Matvec v = A[idx] @ s.  Thread t: row i = t>>2, quarter q = t&3
    // reads 16 consecutive floats (4x float4), lanes stride 64B -> full row streamed.
    const int i = t >> 2;
    const int q = t & 3;
    const float* Abase = A + (size_t)idx * (CDIM * CDIM) + (size_t)(i * CDIM + q * 16);
    float acc = 0.0f;
    #pragma unroll
    for (int k = 0; k < 4; ++k) {
        float4 a = reinterpret_cast<const float4*>(Abase)[k];
        const int j = q * 16 + k * 4;
        acc = fmaf(a.x, s_sh[j + 0], acc);
        acc = fmaf(a.y, s_sh[j + 1], acc);
        acc = fmaf(a.z, s_sh[j + 2], acc);
        acc = fmaf(a.w, s_sh[j + 3], acc);
    }
    // reduce the 4 quarter-partials (lanes t, t^1, t^2 share row i)
    acc += __shfl_xor(acc, 1);
    acc += __shfl_xor(acc, 2);

    float val = ce_part;
    if (q == 0) val += gate * (-acc * ls_sh[i]);

    // block reduce 256 -> 1
    #pragma unroll
    for (int o = 32; o >= 1; o >>= 1) val += __shfl_xor(val, o);
    if ((t & 63) == 0) red[t >> 6] = val;
    __syncthreads();
    if (t == 0) partial[b] = red[0] + red[1] + red[2] + red[3];
}

__global__ __launch_bounds__(256) void lrt_stage2(
    const float* __restrict__ partial, float* __restrict__ out, int n)
{
    const int t = threadIdx.x;
    double acc = 0.0;
    for (int i = t; i < n; i += 256) acc += (double)partial[i];
    #pragma unroll
    for (int o = 32; o >= 1; o >>= 1) acc += __shfl_xor(acc, o);
    __shared__ double red[4];
    if ((t & 63) == 0) red[t >> 6] = acc;
    __syncthreads();
    if (t == 0) out[0] = (float)((red[0] + red[1] + red[2] + red[3]) / (double)n);
}

extern "C" void kernel_launch(void* const* d_in, const int* in_sizes, int n_in,
                              void* d_out, int out_size, void* d_ws, size_t ws_size,
                              hipStream_t stream) {
    const float* outputs     = (const float*)d_in[0];
    const float* targets     = (const float*)d_in[1];
    const float* A           = (const float*)d_in[2];
    const float* soft_labels = (const float*)d_in[3];
    const int*   epoch       = (const int*)d_in[4];
    const int*   index       = (const int*)d_in[5];

    const int B = in_sizes[5];          // 8192 samples (index length)
    float* partial = (float*)d_ws;      // B floats of scratch, overwritten each call

    lrt_stage1<<<B, 256, 0, stream>>>(outputs, targets, A, soft_labels,
                                      epoch, index, partial);
    lrt_stage2<<<1, 256, 0, stream>>>(partial, (float*)d_out, B);
}

// Round 2
// 33.844 us; speedup vs baseline: 1.0608x; 1.0608x over previous
//
#include <hip/hip_runtime.h>

// LRT loss: ce  = -(log_softmax(outputs) * targets).sum()/B
//           lrt = -((A[index] @ soft_labels[index]) * log_softmax(outputs)).sum()/B
// out = ce + (epoch >= 10 ? lrt : 0)
// B=8192, C=64, A is [N,64,64] f32. Memory-bound: 134 MB gathered A rows.
//
// Structure: one wave (64 lanes) = one sample, no LDS in hot path.
//   lane = class for softmax/CE; lane = row for the 64x64 matvec.
//   soft_labels broadcast via constant-lane __shfl (no barrier).
// Grid 2048 x 256 thr, __launch_bounds__(256,8) -> 8 blocks/CU, all waves
// co-resident in one round -> max outstanding HBM loads.

#define CDIM 64

__global__ __launch_bounds__(256, 8) void lrt_stage1(
    const float* __restrict__ outputs,
    const float* __restrict__ targets,
    const float* __restrict__ A,
    const float* __restrict__ soft_labels,
    const int* __restrict__ epoch,
    const int* __restrict__ index,
    float* __restrict__ partial,
    int B)
{
    const int w = threadIdx.x >> 6;   // wave in block (0..3)
    const int l = threadIdx.x & 63;   // lane = class / row
    const int b = blockIdx.x * 4 + w; // sample

    float val = 0.0f;
    if (b < B) {                       // wave-uniform
        const int idx = index[b];
        const float gate = (epoch[0] >= 10) ? 1.0f : 0.0f;

        // independent loads — issue early, overlap with softmax
        const float x  = outputs[(size_t)b * CDIM + l];
        const float tg = targets[(size_t)b * CDIM + l];
        const float sv = soft_labels[(size_t)idx * CDIM + l];
        const float4* __restrict__ Arow =
            reinterpret_cast<const float4*>(A + (size_t)idx * (CDIM * CDIM) + l * CDIM);

        // wave softmax (lane = class)
        float m = x;
        #pragma unroll
        for (int o = 32; o >= 1; o >>= 1) m = fmaxf(m, __shfl_xor(m, o));
        float e = expf(x - m);
        float s = e;
        #pragma unroll
        for (int o = 32; o >= 1; o >>= 1) s += __shfl_xor(s, o);
        const float ls = x - m - logf(s);   // log_softmax[b][l]

        // matvec row l: acc = sum_j A[l][j] * s[j]; s[j] broadcast from lane j
        float acc = 0.0f;
        #pragma unroll
        for (int c = 0; c < 4; ++c) {
            #pragma unroll
            for (int u = 0; u < 4; ++u) {
                const float4 a = Arow[c * 4 + u];
                const int j = c * 16 + u * 4;
                acc = fmaf(a.x, __shfl(sv, j + 0), acc);
                acc = fmaf(a.y, __shfl(sv, j + 1), acc);
                acc = fmaf(a.z, __shfl(sv, j + 2), acc);
                acc = fmaf(a.w, __shfl(sv, j + 3), acc);
            }
        }

        // per-lane contribution: CE term + gated LRT term (ls, acc both lane-local)
        val = -ls * tg + gate * (-acc * ls);
    }

    // wave reduce
    #pragma unroll
    for (int o = 32; o >= 1; o >>= 1) val += __shfl_xor(val, o);

    __shared__ float red[4];
    if (l == 0) red[w] = val;
    __syncthreads();
    if (threadIdx.x == 0)
        partial[blockIdx.x] = red[0] + red[1] + red[2] + red[3];
}

__global__ __launch_bounds__(256) void lrt_stage2(
    const float* __restrict__ partial, float* __restrict__ out, int n, int B)
{
    const int t = threadIdx.x;
    double acc = 0.0;
    for (int i = t; i < n; i += 256) acc += (double)partial[i];
    #pragma unroll
    for (int o = 32; o >= 1; o >>= 1) acc += __shfl_xor(acc, o);
    __shared__ double red[4];
    if ((t & 63) == 0) red[t >> 6] = acc;
    __syncthreads();
    if (t == 0) out[0] = (float)((red[0] + red[1] + red[2] + red[3]) / (double)B);
}

extern "C" void kernel_launch(void* const* d_in, const int* in_sizes, int n_in,
                              void* d_out, int out_size, void* d_ws, size_t ws_size,
                              hipStream_t stream) {
    const float* outputs     = (const float*)d_in[0];
    const float* targets     = (const float*)d_in[1];
    const float* A           = (const float*)d_in[2];
    const float* soft_labels = (const float*)d_in[3];
    const int*   epoch       = (const int*)d_in[4];
    const int*   index       = (const int*)d_in[5];

    const int B = in_sizes[5];              // 8192 samples
    const int nblocks = (B + 3) / 4;        // one wave per sample, 4 waves/block
    float* partial = (float*)d_ws;          // nblocks floats, fully overwritten each call

    lrt_stage1<<<nblocks, 256, 0, stream>>>(outputs, targets, A, soft_labels,
                                            epoch, index, partial, B);
    lrt_stage2<<<1, 256, 0, stream>>>(partial, (float*)d_out, nblocks, B);
}